// Round 2
// baseline (158.559 us; speedup 1.0000x reference)
//
#include <hip/hip_runtime.h>

#define FG_THRESH 0.7f
#define BG_HI 0.5f
#define BG_LO 0.1f
#define BATCH 256
#define FG_ROIS 128
#define KGT 256
#define CLS 81

// One fused kernel. Grid = M/64 blocks of 256 threads.
// Phase 1: IoU max/argmax, 4 lanes per roi (lane covers k = c mod 4), exact
//          per-element IEEE division, first-of-max merge via shfl butterfly.
// Phase 2 (last finishing block only, via fence+atomic counter): popcount-scan
//          the per-block fg/bg/nonbg bitmasks, extract ordered candidate lists,
//          build keep/meta, write all outputs.
__global__ __launch_bounds__(256) void k_fused(
    const float* __restrict__ proposals,   // (N,4)
    const float* __restrict__ gt_boxes,    // (K,4)
    const float* __restrict__ gt_labels,   // (K,C)
    int N, int M, int GB,
    int* __restrict__ gt_assign,           // [M]
    unsigned long long* __restrict__ fgm,  // [GB]
    unsigned long long* __restrict__ bgm,  // [GB]
    unsigned long long* __restrict__ nbm,  // [GB]
    int* __restrict__ done_ctr,
    float* __restrict__ out_rois,          // (BATCH,4)
    float* __restrict__ out_labels,        // (BATCH,C)
    float* __restrict__ out_bbox)          // (BATCH,4C)
{
    __shared__ float4 gsh[KGT];
    __shared__ float garea[KGT];
    __shared__ unsigned long long wm[3][4];
    __shared__ int sLast;

    int tid = threadIdx.x;

    // stage gt boxes (K == 256 == blockDim)
    {
        float4 g = ((const float4*)gt_boxes)[tid];
        gsh[tid] = g;
        garea[tid] = (g.z - g.x + 1.0f) * (g.w - g.y + 1.0f);
    }
    __syncthreads();

    int wv = tid >> 6, lane = tid & 63;
    int c = lane & 3;          // k-class (k mod 4)
    int rj = lane >> 2;        // roi within wave, 0..15
    int roi = blockIdx.x * 64 + wv * 16 + rj;

    float best = -1.0f;
    int bestk = 0;
    {
        float4 a;
        if (roi < M) a = (roi < N) ? ((const float4*)proposals)[roi]
                                   : ((const float4*)gt_boxes)[roi - N];
        else         a = gsh[0];   // dummy, flags masked later
        float area_a = (a.z - a.x + 1.0f) * (a.w - a.y + 1.0f);
        #pragma unroll 4
        for (int j = 0; j < KGT / 4; ++j) {
            int k = (j << 2) | c;
            float4 g = gsh[k];
            float x1 = fmaxf(a.x, g.x);
            float y1 = fmaxf(a.y, g.y);
            float x2 = fminf(a.z, g.z);
            float y2 = fminf(a.w, g.w);
            float iw = fmaxf(x2 - x1 + 1.0f, 0.0f);
            float ih = fmaxf(y2 - y1 + 1.0f, 0.0f);
            float inter = iw * ih;
            float ov = inter / (area_a + garea[k] - inter);  // IEEE div = np
            if (ov > best) { best = ov; bestk = k; }          // first-of-max in class
        }
    }
    // merge the 4 k-classes: max ov, tie -> lower k (== np first-of-max)
    #pragma unroll
    for (int d = 1; d < 4; d <<= 1) {
        float ob = __shfl_xor(best, d);
        int   kb = __shfl_xor(bestk, d);
        if (ob > best || (ob == best && kb < bestk)) { best = ob; bestk = kb; }
    }
    // compact: lane j<16 pulls result of roi j (source lane 4*j)
    float bset = __shfl(best, (lane & 15) * 4);
    int   bk   = __shfl(bestk, (lane & 15) * 4);

    int roi2 = blockIdx.x * 64 + wv * 16 + (lane & 15);
    bool isv = (lane < 16) && (roi2 < M);
    bool fgp = isv && (bset >= FG_THRESH);
    bool bgp = isv && (bset < BG_HI) && (bset >= BG_LO);
    bool nbp = isv && !bgp;
    if (isv) gt_assign[roi2] = bk;

    unsigned long long mf = __ballot(fgp) & 0xFFFFull;
    unsigned long long mb = __ballot(bgp) & 0xFFFFull;
    unsigned long long mn = __ballot(nbp) & 0xFFFFull;
    if (lane == 0) { wm[0][wv] = mf; wm[1][wv] = mb; wm[2][wv] = mn; }
    __syncthreads();
    if (tid == 0) {
        fgm[blockIdx.x] = wm[0][0] | (wm[0][1] << 16) | (wm[0][2] << 32) | (wm[0][3] << 48);
        bgm[blockIdx.x] = wm[1][0] | (wm[1][1] << 16) | (wm[1][2] << 32) | (wm[1][3] << 48);
        nbm[blockIdx.x] = wm[2][0] | (wm[2][1] << 16) | (wm[2][2] << 32) | (wm[2][3] << 48);
    }

    // publish + elect last block
    __threadfence();
    __syncthreads();
    if (tid == 0) sLast = (atomicAdd(done_ctr, 1) == GB - 1) ? 1 : 0;
    __syncthreads();
    if (!sLast) return;
    __threadfence();

    // ---------------- last block: selection + meta + outputs ----------------
    __shared__ int s0[256], s1[256], s2[256];
    __shared__ int fgl[FG_ROIS], bgl[BATCH], nbl[BATCH];
    __shared__ int mfg[BATCH], mcls[BATCH], mga[BATCH];
    __shared__ float mt[BATCH][4];

    int CPT = (GB + 255) >> 8;           // words per thread (5 for GB=1254)
    int lo = tid * CPT, hi = min(lo + CPT, GB);
    int pc0 = 0, pc1 = 0, pc2 = 0;
    for (int w = lo; w < hi; ++w) {
        pc0 += __popcll(fgm[w]);
        pc1 += __popcll(bgm[w]);
        pc2 += __popcll(nbm[w]);
    }
    s0[tid] = pc0; s1[tid] = pc1; s2[tid] = pc2;
    __syncthreads();
    for (int off = 1; off < 256; off <<= 1) {
        int a0 = (tid >= off) ? s0[tid - off] : 0;
        int a1 = (tid >= off) ? s1[tid - off] : 0;
        int a2 = (tid >= off) ? s2[tid - off] : 0;
        __syncthreads();
        s0[tid] += a0; s1[tid] += a1; s2[tid] += a2;
        __syncthreads();
    }
    int b0 = s0[tid] - pc0, b1 = s1[tid] - pc1, b2 = s2[tid] - pc2;
    int num_fg = s0[255], num_bg = s1[255];

    // extract first FG_ROIS fg / BATCH bg / BATCH nonbg, ascending index
    for (int w = lo; w < hi; ++w) {
        unsigned long long m = fgm[w];
        while (m) {
            if (b0 >= FG_ROIS) break;
            int b = __ffsll(m) - 1;
            fgl[b0++] = (w << 6) + b;
            m &= m - 1;
        }
        m = bgm[w];
        while (m) {
            if (b1 >= BATCH) break;
            int b = __ffsll(m) - 1;
            bgl[b1++] = (w << 6) + b;
            m &= m - 1;
        }
        m = nbm[w];
        while (m) {
            if (b2 >= BATCH) break;
            int b = __ffsll(m) - 1;
            nbl[b2++] = (w << 6) + b;
            m &= m - 1;
        }
    }
    __syncthreads();

    // meta: pos = tid (0..255)
    {
        int pos = tid;
        int fg_take = min(FG_ROIS, num_fg);
        int is_fg = (pos < fg_take) ? 1 : 0;
        int j = pos - fg_take;
        int keep = is_fg ? fgl[pos] : ((j < num_bg) ? bgl[j] : nbl[j - num_bg]);

        float4 a = (keep < N) ? ((const float4*)proposals)[keep] : gsh[keep - N];
        int ga = gt_assign[keep];
        float4 g = gsh[ga];

        float ew = a.z - a.x + 1.0f, eh = a.w - a.y + 1.0f;
        float ecx = a.x + 0.5f * ew, ecy = a.y + 0.5f * eh;
        float gw = g.z - g.x + 1.0f, gh = g.w - g.y + 1.0f;
        float gcx = g.x + 0.5f * gw, gcy = g.y + 0.5f * gh;

        int cls = 0;
        if (is_fg) {
            const float* lr = gt_labels + (size_t)ga * CLS;
            float bv = lr[0]; int bi = 0;
            for (int cc = 1; cc < CLS; ++cc) {
                float v = lr[cc];
                if (v > bv) { bv = v; bi = cc; }
            }
            cls = bi;
        }

        mfg[pos] = is_fg;
        mcls[pos] = cls;
        mga[pos] = ga;
        mt[pos][0] = (gcx - ecx) / ew;
        mt[pos][1] = (gcy - ecy) / eh;
        mt[pos][2] = logf(gw / ew);
        mt[pos][3] = logf(gh / eh);

        out_rois[pos * 4 + 0] = a.x;
        out_rois[pos * 4 + 1] = a.y;
        out_rois[pos * 4 + 2] = a.z;
        out_rois[pos * 4 + 3] = a.w;
    }
    __syncthreads();

    // outputs: labels (BATCH x C), bbox targets (BATCH x 4C)
    for (int e = tid; e < BATCH * CLS; e += 256) {
        int pos = e / CLS, cc = e - pos * CLS;
        out_labels[e] = mfg[pos] ? gt_labels[(size_t)mga[pos] * CLS + cc]
                                 : (cc == 0 ? 1.0f : 0.0f);
    }
    for (int e = tid; e < BATCH * 4 * CLS; e += 256) {
        int pos = e / (4 * CLS), idx = e - pos * (4 * CLS);
        int cc = idx >> 2, d = idx & 3;
        int cl = mcls[pos];
        out_bbox[e] = (cl > 0 && cc == cl) ? mt[pos][d] : 0.0f;
    }
}

extern "C" void kernel_launch(void* const* d_in, const int* in_sizes, int n_in,
                              void* d_out, int out_size, void* d_ws, size_t ws_size,
                              hipStream_t stream)
{
    const float* proposals = (const float*)d_in[0];
    const float* gt_labels = (const float*)d_in[1];
    const float* gt_boxes  = (const float*)d_in[2];
    int N = in_sizes[0] / 4;           // 80000
    int K = in_sizes[2] / 4;           // 256
    int M = N + K;                     // 80256
    int GB = (M + 63) / 64;            // 1254

    char* ws = (char*)d_ws;
    size_t off = 0;
    auto alloc = [&](size_t bytes) -> void* {
        void* p = ws + off;
        off += (bytes + 255) & ~(size_t)255;
        return p;
    };
    int* done_ctr = (int*)alloc(4);
    int* gt_assign = (int*)alloc((size_t)M * 4);
    unsigned long long* fgm = (unsigned long long*)alloc((size_t)GB * 8);
    unsigned long long* bgm = (unsigned long long*)alloc((size_t)GB * 8);
    unsigned long long* nbm = (unsigned long long*)alloc((size_t)GB * 8);

    float* out_rois   = (float*)d_out;
    float* out_labels = out_rois + BATCH * 4;
    float* out_bbox   = out_labels + BATCH * CLS;

    hipMemsetAsync(done_ctr, 0, 4, stream);
    k_fused<<<GB, 256, 0, stream>>>(proposals, gt_boxes, gt_labels,
                                    N, M, GB, gt_assign, fgm, bgm, nbm,
                                    done_ctr, out_rois, out_labels, out_bbox);
    (void)K; (void)n_in; (void)out_size; (void)ws_size;
}

// Round 3
// 74.120 us; speedup vs baseline: 2.1392x; 2.1392x over previous
//
#include <hip/hip_runtime.h>

#define FG_THRESH 0.7f
#define BG_HI 0.5f
#define BG_LO 0.1f
#define BATCH 256
#define FG_ROIS 128
#define KGT 256
#define CLS 81

// ---------------------------------------------------------------------------
// A: IoU max/argmax. 4 lanes per roi (lane covers k = c mod 4), exact IEEE
//    division, first-of-max merge via shfl butterfly (bit-validated vs np in
//    rounds 1-2). Each block handles exactly 2 chunks of 64 rois.
//    Emits gt_assign[M] and per-chunk 64-bit fg/bg/nonbg masks.
// ---------------------------------------------------------------------------
__global__ __launch_bounds__(256) void k_iou(
    const float* __restrict__ proposals,   // (N,4)
    const float* __restrict__ gt_boxes,    // (K,4)
    int N, int M, int NCH, int NB,
    int* __restrict__ gt_assign,           // [M]
    unsigned long long* __restrict__ fgm,  // [NCH]
    unsigned long long* __restrict__ bgm,  // [NCH]
    unsigned long long* __restrict__ nbm)  // [NCH]
{
    __shared__ float4 gsh[KGT];
    __shared__ float garea[KGT];
    __shared__ unsigned int wm[3][4];

    int tid = threadIdx.x;
    {
        float4 g = ((const float4*)gt_boxes)[tid];
        gsh[tid] = g;
        garea[tid] = (g.z - g.x + 1.0f) * (g.w - g.y + 1.0f);
    }
    __syncthreads();

    int wv = tid >> 6, lane = tid & 63;
    int c = lane & 3;          // k-class (k mod 4)
    int rj = lane >> 2;        // roi within wave, 0..15

    for (int p = 0; p < 2; ++p) {
        int ch = blockIdx.x + NB * p;
        if (ch >= NCH) break;                      // block-uniform
        int roi = ch * 64 + wv * 16 + rj;

        float best = -1.0f;
        int bestk = 0;
        {
            float4 a;
            if (roi < M) a = (roi < N) ? ((const float4*)proposals)[roi]
                                       : gsh[roi - N];
            else         a = gsh[0];               // dummy, masked below
            float area_a = (a.z - a.x + 1.0f) * (a.w - a.y + 1.0f);
            #pragma unroll 4
            for (int j = 0; j < KGT / 4; ++j) {
                int k = (j << 2) | c;
                float4 g = gsh[k];
                float x1 = fmaxf(a.x, g.x);
                float y1 = fmaxf(a.y, g.y);
                float x2 = fminf(a.z, g.z);
                float y2 = fminf(a.w, g.w);
                float iw = fmaxf(x2 - x1 + 1.0f, 0.0f);
                float ih = fmaxf(y2 - y1 + 1.0f, 0.0f);
                float inter = iw * ih;
                float ov = inter / (area_a + garea[k] - inter);  // IEEE div = np
                if (ov > best) { best = ov; bestk = k; }
            }
        }
        // merge 4 k-classes: max ov, tie -> lower k  (== np first-of-max)
        #pragma unroll
        for (int d = 1; d < 4; d <<= 1) {
            float ob = __shfl_xor(best, d);
            int   kb = __shfl_xor(bestk, d);
            if (ob > best || (ob == best && kb < bestk)) { best = ob; bestk = kb; }
        }
        // compact: lane j<16 pulls result of roi j (source lane 4*j)
        float bset = __shfl(best, (lane & 15) * 4);
        int   bk   = __shfl(bestk, (lane & 15) * 4);

        int roi2 = ch * 64 + wv * 16 + (lane & 15);
        bool isv = (lane < 16) && (roi2 < M);
        bool fgp = isv && (bset >= FG_THRESH);
        bool bgp = isv && (bset < BG_HI) && (bset >= BG_LO);
        bool nbp = isv && !bgp;
        if (isv) gt_assign[roi2] = bk;

        unsigned int mf = (unsigned int)(__ballot(fgp) & 0xFFFFull);
        unsigned int mb = (unsigned int)(__ballot(bgp) & 0xFFFFull);
        unsigned int mn = (unsigned int)(__ballot(nbp) & 0xFFFFull);
        if (lane == 0) { wm[0][wv] = mf; wm[1][wv] = mb; wm[2][wv] = mn; }
        __syncthreads();
        if (tid == 0) {
            fgm[ch] = (unsigned long long)wm[0][0]        | ((unsigned long long)wm[0][1] << 16)
                    | ((unsigned long long)wm[0][2] << 32) | ((unsigned long long)wm[0][3] << 48);
            bgm[ch] = (unsigned long long)wm[1][0]        | ((unsigned long long)wm[1][1] << 16)
                    | ((unsigned long long)wm[1][2] << 32) | ((unsigned long long)wm[1][3] << 48);
            nbm[ch] = (unsigned long long)wm[2][0]        | ((unsigned long long)wm[2][1] << 16)
                    | ((unsigned long long)wm[2][2] << 32) | ((unsigned long long)wm[2][3] << 48);
        }
        __syncthreads();
    }
}

// ---------------------------------------------------------------------------
// B: single block, 256 threads. Scan masks -> ordered candidate lists ->
//    keep/meta -> all outputs. Intra-block sync only.
// ---------------------------------------------------------------------------
__global__ __launch_bounds__(256) void k_select(
    const float* __restrict__ proposals,
    const float* __restrict__ gt_boxes,
    const float* __restrict__ gt_labels,   // (K,C)
    int N, int NCH,
    const int* __restrict__ gt_assign,
    const unsigned long long* __restrict__ fgm,
    const unsigned long long* __restrict__ bgm,
    const unsigned long long* __restrict__ nbm,
    float* __restrict__ out_rois,          // (BATCH,4)
    float* __restrict__ out_labels,        // (BATCH,C)
    float* __restrict__ out_bbox)          // (BATCH,4C)
{
    __shared__ float4 gsh[KGT];
    __shared__ int s0[256], s1[256], s2[256];
    __shared__ int fgl[FG_ROIS], bgl[BATCH], nbl[BATCH];
    __shared__ int mfg[BATCH], mcls[BATCH], mga[BATCH];
    __shared__ float4 mt4[BATCH];

    int tid = threadIdx.x;
    gsh[tid] = ((const float4*)gt_boxes)[tid];

    int CPT = (NCH + 255) >> 8;            // words per thread (5 @ NCH=1254)
    int lo = tid * CPT, hi = min(lo + CPT, NCH);
    int pc0 = 0, pc1 = 0, pc2 = 0;
    for (int w = lo; w < hi; ++w) {
        pc0 += __popcll(fgm[w]);
        pc1 += __popcll(bgm[w]);
        pc2 += __popcll(nbm[w]);
    }
    s0[tid] = pc0; s1[tid] = pc1; s2[tid] = pc2;
    __syncthreads();
    for (int off = 1; off < 256; off <<= 1) {
        int a0 = (tid >= off) ? s0[tid - off] : 0;
        int a1 = (tid >= off) ? s1[tid - off] : 0;
        int a2 = (tid >= off) ? s2[tid - off] : 0;
        __syncthreads();
        s0[tid] += a0; s1[tid] += a1; s2[tid] += a2;
        __syncthreads();
    }
    int b0 = s0[tid] - pc0, b1 = s1[tid] - pc1, b2 = s2[tid] - pc2;
    int num_fg = s0[255], num_bg = s1[255];

    // extract first FG_ROIS fg / BATCH bg / BATCH nonbg, ascending roi index
    for (int w = lo; w < hi; ++w) {
        unsigned long long m = fgm[w];
        while (m && b0 < FG_ROIS) {
            fgl[b0++] = (w << 6) + __ffsll(m) - 1;
            m &= m - 1;
        }
        m = bgm[w];
        while (m && b1 < BATCH) {
            bgl[b1++] = (w << 6) + __ffsll(m) - 1;
            m &= m - 1;
        }
        m = nbm[w];
        while (m && b2 < BATCH) {
            nbl[b2++] = (w << 6) + __ffsll(m) - 1;
            m &= m - 1;
        }
    }
    __syncthreads();

    // meta, pos = tid
    {
        int pos = tid;
        int fg_take = min(FG_ROIS, num_fg);
        int is_fg = (pos < fg_take) ? 1 : 0;
        int j = pos - fg_take;
        int keep = is_fg ? fgl[pos] : ((j < num_bg) ? bgl[j] : nbl[j - num_bg]);

        float4 a = (keep < N) ? ((const float4*)proposals)[keep] : gsh[keep - N];
        int ga = gt_assign[keep];
        float4 g = gsh[ga];

        float ew = a.z - a.x + 1.0f, eh = a.w - a.y + 1.0f;
        float ecx = a.x + 0.5f * ew, ecy = a.y + 0.5f * eh;
        float gw = g.z - g.x + 1.0f, gh = g.w - g.y + 1.0f;
        float gcx = g.x + 0.5f * gw, gcy = g.y + 0.5f * gh;

        int cls = 0;
        if (is_fg) {
            const float* lr = gt_labels + (size_t)ga * CLS;
            float bv = lr[0]; int bi = 0;
            for (int cc = 1; cc < CLS; ++cc) {
                float v = lr[cc];
                if (v > bv) { bv = v; bi = cc; }
            }
            cls = bi;
        }

        mfg[pos] = is_fg;
        mcls[pos] = cls;
        mga[pos] = ga;
        mt4[pos] = make_float4((gcx - ecx) / ew, (gcy - ecy) / eh,
                               logf(gw / ew), logf(gh / eh));
        ((float4*)out_rois)[pos] = a;
    }
    __syncthreads();

    // labels (BATCH x C), coalesced scalar stores
    for (int e = tid; e < BATCH * CLS; e += 256) {
        int pos = e / CLS, cc = e - pos * CLS;
        out_labels[e] = mfg[pos] ? gt_labels[(size_t)mga[pos] * CLS + cc]
                                 : (cc == 0 ? 1.0f : 0.0f);
    }
    // bbox targets (BATCH x 4C), float4 stores (one class-slot per float4)
    for (int e = tid; e < BATCH * CLS; e += 256) {
        int pos = e / CLS, cc = e - pos * CLS;
        int cl = mcls[pos];
        float4 v = (cl > 0 && cc == cl) ? mt4[pos] : make_float4(0.f, 0.f, 0.f, 0.f);
        ((float4*)out_bbox)[e] = v;
    }
}

// ---------------------------------------------------------------------------
extern "C" void kernel_launch(void* const* d_in, const int* in_sizes, int n_in,
                              void* d_out, int out_size, void* d_ws, size_t ws_size,
                              hipStream_t stream)
{
    const float* proposals = (const float*)d_in[0];
    const float* gt_labels = (const float*)d_in[1];
    const float* gt_boxes  = (const float*)d_in[2];
    int N = in_sizes[0] / 4;           // 80000
    int K = in_sizes[2] / 4;           // 256
    int M = N + K;                     // 80256
    int NCH = (M + 63) / 64;           // 1254
    int NB  = (NCH + 1) / 2;           // 627

    char* ws = (char*)d_ws;
    size_t off = 0;
    auto alloc = [&](size_t bytes) -> void* {
        void* p = ws + off;
        off += (bytes + 255) & ~(size_t)255;
        return p;
    };
    int* gt_assign = (int*)alloc((size_t)M * 4);
    unsigned long long* fgm = (unsigned long long*)alloc((size_t)NCH * 8);
    unsigned long long* bgm = (unsigned long long*)alloc((size_t)NCH * 8);
    unsigned long long* nbm = (unsigned long long*)alloc((size_t)NCH * 8);

    float* out_rois   = (float*)d_out;
    float* out_labels = out_rois + BATCH * 4;
    float* out_bbox   = out_labels + BATCH * CLS;

    k_iou<<<NB, 256, 0, stream>>>(proposals, gt_boxes, N, M, NCH, NB,
                                  gt_assign, fgm, bgm, nbm);
    k_select<<<1, 256, 0, stream>>>(proposals, gt_boxes, gt_labels, N, NCH,
                                    gt_assign, fgm, bgm, nbm,
                                    out_rois, out_labels, out_bbox);
    (void)K; (void)n_in; (void)out_size; (void)ws_size;
}

// Round 4
// 55.590 us; speedup vs baseline: 2.8523x; 1.3333x over previous
//
#include <hip/hip_runtime.h>

#define FG_THRESH 0.7f
#define BG_HI 0.5f
#define BG_LO 0.1f
#define BATCH 256
#define FG_ROIS 128
#define KGT 256
#define CLS 81

// ---------------------------------------------------------------------------
// A: IoU max/argmax. 4 lanes per roi (lane covers k = c mod 4), exact IEEE
//    division, first-of-max merge via shfl butterfly (bit-validated r1-r3).
//    Each block handles exactly 2 chunks of 64 rois.
// ---------------------------------------------------------------------------
__global__ __launch_bounds__(256) void k_iou(
    const float* __restrict__ proposals,   // (N,4)
    const float* __restrict__ gt_boxes,    // (K,4)
    int N, int M, int NCH, int NB,
    int* __restrict__ gt_assign,           // [M]
    unsigned long long* __restrict__ fgm,  // [NCH]
    unsigned long long* __restrict__ bgm,  // [NCH]
    unsigned long long* __restrict__ nbm)  // [NCH]
{
    __shared__ float4 gsh[KGT];
    __shared__ float garea[KGT];
    __shared__ unsigned int wm[3][4];

    int tid = threadIdx.x;
    {
        float4 g = ((const float4*)gt_boxes)[tid];
        gsh[tid] = g;
        garea[tid] = (g.z - g.x + 1.0f) * (g.w - g.y + 1.0f);
    }
    __syncthreads();

    int wv = tid >> 6, lane = tid & 63;
    int c = lane & 3;          // k-class (k mod 4)
    int rj = lane >> 2;        // roi within wave, 0..15

    for (int p = 0; p < 2; ++p) {
        int ch = blockIdx.x + NB * p;
        if (ch >= NCH) break;                      // block-uniform
        int roi = ch * 64 + wv * 16 + rj;

        float best = -1.0f;
        int bestk = 0;
        {
            float4 a;
            if (roi < M) a = (roi < N) ? ((const float4*)proposals)[roi]
                                       : gsh[roi - N];
            else         a = gsh[0];               // dummy, masked below
            float area_a = (a.z - a.x + 1.0f) * (a.w - a.y + 1.0f);
            #pragma unroll 4
            for (int j = 0; j < KGT / 4; ++j) {
                int k = (j << 2) | c;
                float4 g = gsh[k];
                float x1 = fmaxf(a.x, g.x);
                float y1 = fmaxf(a.y, g.y);
                float x2 = fminf(a.z, g.z);
                float y2 = fminf(a.w, g.w);
                float iw = fmaxf(x2 - x1 + 1.0f, 0.0f);
                float ih = fmaxf(y2 - y1 + 1.0f, 0.0f);
                float inter = iw * ih;
                float ov = inter / (area_a + garea[k] - inter);  // IEEE div = np
                if (ov > best) { best = ov; bestk = k; }
            }
        }
        #pragma unroll
        for (int d = 1; d < 4; d <<= 1) {
            float ob = __shfl_xor(best, d);
            int   kb = __shfl_xor(bestk, d);
            if (ob > best || (ob == best && kb < bestk)) { best = ob; bestk = kb; }
        }
        float bset = __shfl(best, (lane & 15) * 4);
        int   bk   = __shfl(bestk, (lane & 15) * 4);

        int roi2 = ch * 64 + wv * 16 + (lane & 15);
        bool isv = (lane < 16) && (roi2 < M);
        bool fgp = isv && (bset >= FG_THRESH);
        bool bgp = isv && (bset < BG_HI) && (bset >= BG_LO);
        bool nbp = isv && !bgp;
        if (isv) gt_assign[roi2] = bk;

        unsigned int mf = (unsigned int)(__ballot(fgp) & 0xFFFFull);
        unsigned int mb = (unsigned int)(__ballot(bgp) & 0xFFFFull);
        unsigned int mn = (unsigned int)(__ballot(nbp) & 0xFFFFull);
        if (lane == 0) { wm[0][wv] = mf; wm[1][wv] = mb; wm[2][wv] = mn; }
        __syncthreads();
        if (tid == 0) {
            fgm[ch] = (unsigned long long)wm[0][0]        | ((unsigned long long)wm[0][1] << 16)
                    | ((unsigned long long)wm[0][2] << 32) | ((unsigned long long)wm[0][3] << 48);
            bgm[ch] = (unsigned long long)wm[1][0]        | ((unsigned long long)wm[1][1] << 16)
                    | ((unsigned long long)wm[1][2] << 32) | ((unsigned long long)wm[1][3] << 48);
            nbm[ch] = (unsigned long long)wm[2][0]        | ((unsigned long long)wm[2][1] << 16)
                    | ((unsigned long long)wm[2][2] << 32) | ((unsigned long long)wm[2][3] << 48);
        }
        __syncthreads();
    }
}

// ---------------------------------------------------------------------------
// B: single block, 256 threads. ONLY the tiny serial work: mask scan (words
//    preloaded to registers, one vmcnt wait), ordered extract, meta + rois.
//    Meta goes to ws for the parallel writer kernel.
// ---------------------------------------------------------------------------
__global__ __launch_bounds__(256) void k_meta(
    const float* __restrict__ proposals,
    const float* __restrict__ gt_boxes,
    const float* __restrict__ gt_labels,   // (K,C)
    int N, int NCH,
    const int* __restrict__ gt_assign,
    const unsigned long long* __restrict__ fgm,
    const unsigned long long* __restrict__ bgm,
    const unsigned long long* __restrict__ nbm,
    int4* __restrict__ meta_i,             // [BATCH] (is_fg, cls, ga, 0)
    float4* __restrict__ meta_t,           // [BATCH] (tx,ty,tw,th)
    float* __restrict__ out_rois)          // (BATCH,4)
{
    __shared__ float4 gsh[KGT];
    __shared__ int s0[256], s1[256], s2[256];
    __shared__ int fgl[FG_ROIS], bgl[BATCH], nbl[BATCH];

    int tid = threadIdx.x;
    gsh[tid] = ((const float4*)gt_boxes)[tid];

    const int CPT = 5;                       // covers NCH<=1280
    int lo = tid * CPT, hi = min(lo + CPT, NCH);
    unsigned long long wf[CPT], wb[CPT], wn[CPT];
    #pragma unroll
    for (int r = 0; r < CPT; ++r) {
        int idx = lo + r;
        bool v = (idx < NCH);
        wf[r] = v ? fgm[idx] : 0ull;
        wb[r] = v ? bgm[idx] : 0ull;
        wn[r] = v ? nbm[idx] : 0ull;
    }
    int pc0 = 0, pc1 = 0, pc2 = 0;
    #pragma unroll
    for (int r = 0; r < CPT; ++r) {
        pc0 += __popcll(wf[r]);
        pc1 += __popcll(wb[r]);
        pc2 += __popcll(wn[r]);
    }
    s0[tid] = pc0; s1[tid] = pc1; s2[tid] = pc2;
    __syncthreads();
    for (int off = 1; off < 256; off <<= 1) {
        int a0 = (tid >= off) ? s0[tid - off] : 0;
        int a1 = (tid >= off) ? s1[tid - off] : 0;
        int a2 = (tid >= off) ? s2[tid - off] : 0;
        __syncthreads();
        s0[tid] += a0; s1[tid] += a1; s2[tid] += a2;
        __syncthreads();
    }
    int b0 = s0[tid] - pc0, b1 = s1[tid] - pc1, b2 = s2[tid] - pc2;
    int num_fg = s0[255], num_bg = s1[255];

    #pragma unroll
    for (int r = 0; r < CPT; ++r) {
        int w = lo + r;
        unsigned long long m = wf[r];
        while (m && b0 < FG_ROIS) {
            fgl[b0++] = (w << 6) + __ffsll(m) - 1;
            m &= m - 1;
        }
        m = wb[r];
        while (m && b1 < BATCH) {
            bgl[b1++] = (w << 6) + __ffsll(m) - 1;
            m &= m - 1;
        }
        m = wn[r];
        while (m && b2 < BATCH) {
            nbl[b2++] = (w << 6) + __ffsll(m) - 1;
            m &= m - 1;
        }
    }
    __syncthreads();

    int pos = tid;
    int fg_take = min(FG_ROIS, num_fg);
    int is_fg = (pos < fg_take) ? 1 : 0;
    int j = pos - fg_take;
    int keep = is_fg ? fgl[pos] : ((j < num_bg) ? bgl[j] : nbl[j - num_bg]);

    float4 a = (keep < N) ? ((const float4*)proposals)[keep] : gsh[keep - N];
    int ga = gt_assign[keep];
    float4 g = gsh[ga];

    float ew = a.z - a.x + 1.0f, eh = a.w - a.y + 1.0f;
    float ecx = a.x + 0.5f * ew, ecy = a.y + 0.5f * eh;
    float gw = g.z - g.x + 1.0f, gh = g.w - g.y + 1.0f;
    float gcx = g.x + 0.5f * gw, gcy = g.y + 0.5f * gh;

    int cls = 0;
    if (is_fg) {
        const float* lr = gt_labels + (size_t)ga * CLS;
        float bv = lr[0]; int bi = 0;
        for (int cc = 1; cc < CLS; ++cc) {
            float v = lr[cc];
            if (v > bv) { bv = v; bi = cc; }
        }
        cls = bi;
    }

    meta_i[pos] = make_int4(is_fg, cls, ga, 0);
    meta_t[pos] = make_float4((gcx - ecx) / ew, (gcy - ecy) / eh,
                              logf(gw / ew), logf(gh / eh));
    ((float4*)out_rois)[pos] = a;
}

// ---------------------------------------------------------------------------
// C: parallel output fan-out. 81 blocks x 256: each thread writes one label
//    element and one bbox float4 (class slot).
// ---------------------------------------------------------------------------
__global__ __launch_bounds__(256) void k_out(
    const float* __restrict__ gt_labels,
    const int4* __restrict__ meta_i,
    const float4* __restrict__ meta_t,
    float* __restrict__ out_labels,        // (BATCH*CLS)
    float4* __restrict__ out_bbox)         // (BATCH*CLS) float4 slots
{
    int e = blockIdx.x * 256 + threadIdx.x;
    if (e >= BATCH * CLS) return;
    int pos = e / CLS, cc = e - pos * CLS;
    int4 mi = meta_i[pos];                 // (is_fg, cls, ga, 0)
    out_labels[e] = mi.x ? gt_labels[(size_t)mi.z * CLS + cc]
                         : (cc == 0 ? 1.0f : 0.0f);
    float4 v = (mi.y > 0 && cc == mi.y) ? meta_t[pos]
                                        : make_float4(0.f, 0.f, 0.f, 0.f);
    out_bbox[e] = v;
}

// ---------------------------------------------------------------------------
extern "C" void kernel_launch(void* const* d_in, const int* in_sizes, int n_in,
                              void* d_out, int out_size, void* d_ws, size_t ws_size,
                              hipStream_t stream)
{
    const float* proposals = (const float*)d_in[0];
    const float* gt_labels = (const float*)d_in[1];
    const float* gt_boxes  = (const float*)d_in[2];
    int N = in_sizes[0] / 4;           // 80000
    int K = in_sizes[2] / 4;           // 256
    int M = N + K;                     // 80256
    int NCH = (M + 63) / 64;           // 1254
    int NB  = (NCH + 1) / 2;           // 627

    char* ws = (char*)d_ws;
    size_t off = 0;
    auto alloc = [&](size_t bytes) -> void* {
        void* p = ws + off;
        off += (bytes + 255) & ~(size_t)255;
        return p;
    };
    int* gt_assign = (int*)alloc((size_t)M * 4);
    unsigned long long* fgm = (unsigned long long*)alloc((size_t)NCH * 8);
    unsigned long long* bgm = (unsigned long long*)alloc((size_t)NCH * 8);
    unsigned long long* nbm = (unsigned long long*)alloc((size_t)NCH * 8);
    int4*   meta_i = (int4*)  alloc(BATCH * 16);
    float4* meta_t = (float4*)alloc(BATCH * 16);

    float* out_rois   = (float*)d_out;
    float* out_labels = out_rois + BATCH * 4;
    float4* out_bbox  = (float4*)(out_labels + BATCH * CLS);

    k_iou<<<NB, 256, 0, stream>>>(proposals, gt_boxes, N, M, NCH, NB,
                                  gt_assign, fgm, bgm, nbm);
    k_meta<<<1, 256, 0, stream>>>(proposals, gt_boxes, gt_labels, N, NCH,
                                  gt_assign, fgm, bgm, nbm,
                                  meta_i, meta_t, out_rois);
    int nb2 = (BATCH * CLS + 255) / 256;   // 81
    k_out<<<nb2, 256, 0, stream>>>(gt_labels, meta_i, meta_t,
                                   out_labels, out_bbox);
    (void)K; (void)n_in; (void)out_size; (void)ws_size;
}

// Round 5
// 49.168 us; speedup vs baseline: 3.2249x; 1.1306x over previous
//
#include <hip/hip_runtime.h>

#define FG_THRESH 0.7f
#define BG_HI 0.5f
#define BG_LO 0.1f
#define BATCH 256
#define FG_ROIS 128
#define KGT 256
#define CLS 81
#define CPT 5                      // mask words per thread (covers NCH<=1280)

// ---------------------------------------------------------------------------
// A: IoU max/argmax. 4 lanes per roi (lane covers k = c mod 4), exact IEEE
//    division, first-of-max merge via shfl butterfly (bit-validated r1-r4).
//    One 64-roi chunk per block (1254 blocks -> ~4.9 waves/SIMD).
// ---------------------------------------------------------------------------
__global__ __launch_bounds__(256) void k_iou(
    const float* __restrict__ proposals,   // (N,4)
    const float* __restrict__ gt_boxes,    // (K,4)
    int N, int M,
    int* __restrict__ gt_assign,           // [M]
    unsigned long long* __restrict__ fgm,  // [NCH]
    unsigned long long* __restrict__ bgm,  // [NCH]
    unsigned long long* __restrict__ nbm)  // [NCH]
{
    __shared__ float4 gsh[KGT];
    __shared__ float garea[KGT];
    __shared__ unsigned int wm[3][4];

    int tid = threadIdx.x;
    {
        float4 g = ((const float4*)gt_boxes)[tid];
        gsh[tid] = g;
        garea[tid] = (g.z - g.x + 1.0f) * (g.w - g.y + 1.0f);
    }
    __syncthreads();

    int wv = tid >> 6, lane = tid & 63;
    int c = lane & 3;          // k-class (k mod 4)
    int rj = lane >> 2;        // roi within wave, 0..15
    int roi = blockIdx.x * 64 + wv * 16 + rj;

    float best = -1.0f;
    int bestk = 0;
    {
        float4 a;
        if (roi < M) a = (roi < N) ? ((const float4*)proposals)[roi]
                                   : gsh[roi - N];
        else         a = gsh[0];               // dummy, masked below
        float area_a = (a.z - a.x + 1.0f) * (a.w - a.y + 1.0f);
        #pragma unroll 4
        for (int j = 0; j < KGT / 4; ++j) {
            int k = (j << 2) | c;
            float4 g = gsh[k];
            float x1 = fmaxf(a.x, g.x);
            float y1 = fmaxf(a.y, g.y);
            float x2 = fminf(a.z, g.z);
            float y2 = fminf(a.w, g.w);
            float iw = fmaxf(x2 - x1 + 1.0f, 0.0f);
            float ih = fmaxf(y2 - y1 + 1.0f, 0.0f);
            float inter = iw * ih;
            float ov = inter / (area_a + garea[k] - inter);  // IEEE div = np
            if (ov > best) { best = ov; bestk = k; }
        }
    }
    #pragma unroll
    for (int d = 1; d < 4; d <<= 1) {
        float ob = __shfl_xor(best, d);
        int   kb = __shfl_xor(bestk, d);
        if (ob > best || (ob == best && kb < bestk)) { best = ob; bestk = kb; }
    }
    float bset = __shfl(best, (lane & 15) * 4);
    int   bk   = __shfl(bestk, (lane & 15) * 4);

    int roi2 = blockIdx.x * 64 + wv * 16 + (lane & 15);
    bool isv = (lane < 16) && (roi2 < M);
    bool fgp = isv && (bset >= FG_THRESH);
    bool bgp = isv && (bset < BG_HI) && (bset >= BG_LO);
    bool nbp = isv && !bgp;                // non-bg (includes fg) == bg_sorted tail
    if (isv) gt_assign[roi2] = bk;

    unsigned int mf = (unsigned int)(__ballot(fgp) & 0xFFFFull);
    unsigned int mb = (unsigned int)(__ballot(bgp) & 0xFFFFull);
    unsigned int mn = (unsigned int)(__ballot(nbp) & 0xFFFFull);
    if (lane == 0) { wm[0][wv] = mf; wm[1][wv] = mb; wm[2][wv] = mn; }
    __syncthreads();
    if (tid == 0) {
        fgm[blockIdx.x] = (unsigned long long)wm[0][0]        | ((unsigned long long)wm[0][1] << 16)
                        | ((unsigned long long)wm[0][2] << 32) | ((unsigned long long)wm[0][3] << 48);
        bgm[blockIdx.x] = (unsigned long long)wm[1][0]        | ((unsigned long long)wm[1][1] << 16)
                        | ((unsigned long long)wm[1][2] << 32) | ((unsigned long long)wm[1][3] << 48);
        nbm[blockIdx.x] = (unsigned long long)wm[2][0]        | ((unsigned long long)wm[2][1] << 16)
                        | ((unsigned long long)wm[2][2] << 32) | ((unsigned long long)wm[2][3] << 48);
    }
}

// ---------------------------------------------------------------------------
// B: 81 blocks. Each block REDUNDANTLY does the tiny scan+extract (masks are
//    only ~30 KB), computes meta for the <=5 pos values its 256-element
//    output slice touches, and writes labels + bbox for that slice.
//    Block 0 additionally writes the 256 rois. No inter-block communication.
// ---------------------------------------------------------------------------
__global__ __launch_bounds__(256) void k_finish(
    const float* __restrict__ proposals,
    const float* __restrict__ gt_boxes,
    const float* __restrict__ gt_labels,   // (K,C)
    int N, int NCH,
    const int* __restrict__ gt_assign,
    const unsigned long long* __restrict__ fgm,
    const unsigned long long* __restrict__ bgm,
    const unsigned long long* __restrict__ nbm,
    float* __restrict__ out_rois,          // (BATCH,4)
    float* __restrict__ out_labels,        // (BATCH*CLS)
    float4* __restrict__ out_bbox)         // (BATCH*CLS) float4 slots
{
    __shared__ int fgl[FG_ROIS], bgl[BATCH], nbl[BATCH];
    __shared__ int wtot[3][4];
    __shared__ int lm_fg[8], lm_ga[8], lm_cls[8];
    __shared__ float4 lm_t[8];

    int tid = threadIdx.x;
    int lane = tid & 63, wv = tid >> 6;

    // preload mask words to registers (one vmcnt wait)
    int lo = tid * CPT;
    unsigned long long wf[CPT], wb[CPT], wn[CPT];
    #pragma unroll
    for (int r = 0; r < CPT; ++r) {
        int idx = lo + r;
        bool v = (idx < NCH);
        wf[r] = v ? fgm[idx] : 0ull;
        wb[r] = v ? bgm[idx] : 0ull;
        wn[r] = v ? nbm[idx] : 0ull;
    }
    int pc0 = 0, pc1 = 0, pc2 = 0;
    #pragma unroll
    for (int r = 0; r < CPT; ++r) {
        pc0 += __popcll(wf[r]);
        pc1 += __popcll(wb[r]);
        pc2 += __popcll(wn[r]);
    }

    // wave inclusive scan (shfl), then cross-wave offsets via LDS
    int i0 = pc0, i1 = pc1, i2 = pc2;
    #pragma unroll
    for (int d = 1; d < 64; d <<= 1) {
        int t0 = __shfl_up(i0, d);
        int t1 = __shfl_up(i1, d);
        int t2 = __shfl_up(i2, d);
        if (lane >= d) { i0 += t0; i1 += t1; i2 += t2; }
    }
    if (lane == 63) { wtot[0][wv] = i0; wtot[1][wv] = i1; wtot[2][wv] = i2; }
    __syncthreads();
    int o0 = 0, o1 = 0, o2 = 0;
    for (int x = 0; x < wv; ++x) { o0 += wtot[0][x]; o1 += wtot[1][x]; o2 += wtot[2][x]; }
    int b0 = o0 + i0 - pc0;      // exclusive prefix
    int b1 = o1 + i1 - pc1;
    int b2 = o2 + i2 - pc2;
    int num_fg = wtot[0][0] + wtot[0][1] + wtot[0][2] + wtot[0][3];
    int num_bg = wtot[1][0] + wtot[1][1] + wtot[1][2] + wtot[1][3];

    // ordered extraction: first FG_ROIS fg / BATCH bg / BATCH nonbg
    #pragma unroll
    for (int r = 0; r < CPT; ++r) {
        int w = lo + r;
        unsigned long long m = wf[r];
        while (m && b0 < FG_ROIS) { fgl[b0++] = (w << 6) + __ffsll(m) - 1; m &= m - 1; }
        m = wb[r];
        while (m && b1 < BATCH)   { bgl[b1++] = (w << 6) + __ffsll(m) - 1; m &= m - 1; }
        m = wn[r];
        while (m && b2 < BATCH)   { nbl[b2++] = (w << 6) + __ffsll(m) - 1; m &= m - 1; }
    }
    __syncthreads();

    int fg_take = min(FG_ROIS, num_fg);
    int eBase = blockIdx.x * 256;
    int posLo = eBase / CLS;
    int posHi = (eBase + 255) / CLS;
    int np = posHi - posLo + 1;            // <= 5

    // meta for this block's pos range
    if (tid < np) {
        int pos = posLo + tid;
        int is_fg = (pos < fg_take) ? 1 : 0;
        int j = pos - fg_take;
        int keep = is_fg ? fgl[pos] : ((j < num_bg) ? bgl[j] : nbl[j - num_bg]);
        float4 a = (keep < N) ? ((const float4*)proposals)[keep]
                              : ((const float4*)gt_boxes)[keep - N];
        int ga = gt_assign[keep];
        float4 g = ((const float4*)gt_boxes)[ga];

        float ew = a.z - a.x + 1.0f, eh = a.w - a.y + 1.0f;
        float ecx = a.x + 0.5f * ew, ecy = a.y + 0.5f * eh;
        float gw = g.z - g.x + 1.0f, gh = g.w - g.y + 1.0f;
        float gcx = g.x + 0.5f * gw, gcy = g.y + 0.5f * gh;

        int cls = 0;
        if (is_fg) {
            const float* lr = gt_labels + (size_t)ga * CLS;
            float bv = lr[0]; int bi = 0;
            for (int cc = 1; cc < CLS; ++cc) {
                float v = lr[cc];
                if (v > bv) { bv = v; bi = cc; }
            }
            cls = bi;
        }
        lm_fg[tid] = is_fg;
        lm_ga[tid] = ga;
        lm_cls[tid] = cls;
        lm_t[tid] = make_float4((gcx - ecx) / ew, (gcy - ecy) / eh,
                                logf(gw / ew), logf(gh / eh));
    }

    // block 0: rois output (box gather only)
    if (blockIdx.x == 0) {
        int pos = tid;
        int is_fg = (pos < fg_take) ? 1 : 0;
        int j = pos - fg_take;
        int keep = is_fg ? fgl[pos] : ((j < num_bg) ? bgl[j] : nbl[j - num_bg]);
        float4 a = (keep < N) ? ((const float4*)proposals)[keep]
                              : ((const float4*)gt_boxes)[keep - N];
        ((float4*)out_rois)[pos] = a;
    }
    __syncthreads();

    // this block's 256 label elements + 256 bbox float4 slots
    int e = eBase + tid;                   // < BATCH*CLS (grid is exact)
    int pos = e / CLS, cc = e - pos * CLS;
    int li = pos - posLo;
    out_labels[e] = lm_fg[li] ? gt_labels[(size_t)lm_ga[li] * CLS + cc]
                              : (cc == 0 ? 1.0f : 0.0f);
    int cl = lm_cls[li];
    out_bbox[e] = (cl > 0 && cc == cl) ? lm_t[li]
                                       : make_float4(0.f, 0.f, 0.f, 0.f);
}

// ---------------------------------------------------------------------------
extern "C" void kernel_launch(void* const* d_in, const int* in_sizes, int n_in,
                              void* d_out, int out_size, void* d_ws, size_t ws_size,
                              hipStream_t stream)
{
    const float* proposals = (const float*)d_in[0];
    const float* gt_labels = (const float*)d_in[1];
    const float* gt_boxes  = (const float*)d_in[2];
    int N = in_sizes[0] / 4;           // 80000
    int K = in_sizes[2] / 4;           // 256
    int M = N + K;                     // 80256
    int NCH = (M + 63) / 64;           // 1254

    char* ws = (char*)d_ws;
    size_t off = 0;
    auto alloc = [&](size_t bytes) -> void* {
        void* p = ws + off;
        off += (bytes + 255) & ~(size_t)255;
        return p;
    };
    int* gt_assign = (int*)alloc((size_t)M * 4);
    unsigned long long* fgm = (unsigned long long*)alloc((size_t)NCH * 8);
    unsigned long long* bgm = (unsigned long long*)alloc((size_t)NCH * 8);
    unsigned long long* nbm = (unsigned long long*)alloc((size_t)NCH * 8);

    float* out_rois   = (float*)d_out;
    float* out_labels = out_rois + BATCH * 4;
    float4* out_bbox  = (float4*)(out_labels + BATCH * CLS);

    k_iou<<<NCH, 256, 0, stream>>>(proposals, gt_boxes, N, M,
                                   gt_assign, fgm, bgm, nbm);
    int nb2 = (BATCH * CLS) / 256;     // 81 exact
    k_finish<<<nb2, 256, 0, stream>>>(proposals, gt_boxes, gt_labels, N, NCH,
                                      gt_assign, fgm, bgm, nbm,
                                      out_rois, out_labels, out_bbox);
    (void)K; (void)n_in; (void)out_size; (void)ws_size;
}